// Round 1
// baseline (74.417 us; speedup 1.0000x reference)
//
#include <hip/hip_runtime.h>
#include <math.h>

#define NC 32
#define NSTEPS 32

constexpr int BLOCK = 256;
constexpr int PTS_PER_THREAD = 4;
constexpr int CHUNK = BLOCK * PTS_PER_THREAD; // 1024 points per block

// Kernel 1: compute Trels coefficients (A = e^a, B = b*phi(a)) for all
// (theta, cell) pairs. n_theta*NC = 256 threads, single block.
__global__ void trels_kernel(const float* __restrict__ theta,
                             const float* __restrict__ basis,
                             float2* __restrict__ trels,
                             int n_theta, int d) {
    int i = threadIdx.x;
    if (i >= n_theta * NC) return;
    int j = i / NC;   // theta index
    int c = i % NC;   // cell index
    float a = 0.0f, b = 0.0f;
    for (int k = 0; k < d; ++k) {
        float th = theta[j * d + k];
        a = fmaf(basis[(2 * c) * d + k],     th, a);
        b = fmaf(basis[(2 * c + 1) * d + k], th, b);
    }
    const float dT = 1.0f / (float)NSTEPS;
    a *= dT;
    b *= dT;
    float A = expf(a);
    // phi(a) = (e^a - 1)/a with stable small-a branch (matches reference)
    float phi = (fabsf(a) < 1e-6f) ? (1.0f + 0.5f * a) : (expm1f(a) / a);
    trels[i] = make_float2(A, b * phi);
}

// Kernel 2: integrate 32 steps. One theta per block group; coefficient
// table (32 float2 = 256B) in LDS; 4 independent points per thread so the
// dependent chains interleave and hide ds_read latency.
__global__ void __launch_bounds__(BLOCK)
step_kernel(const float* __restrict__ points,
            const float2* __restrict__ trels,
            float* __restrict__ out,
            int n_points) {
    __shared__ float2 tab[NC];
    int blocks_per_theta = n_points / CHUNK;
    int j = blockIdx.x / blocks_per_theta;
    int base = (blockIdx.x % blocks_per_theta) * CHUNK + threadIdx.x;

    if (threadIdx.x < NC) tab[threadIdx.x] = trels[j * NC + threadIdx.x];
    __syncthreads();

    float x[PTS_PER_THREAD];
#pragma unroll
    for (int i = 0; i < PTS_PER_THREAD; ++i)
        x[i] = points[base + i * BLOCK];

#pragma unroll
    for (int s = 0; s < NSTEPS; ++s) {
#pragma unroll
        for (int i = 0; i < PTS_PER_THREAD; ++i) {
            int c = (int)floorf(x[i] * (float)NC);
            c = c < 0 ? 0 : (c > NC - 1 ? NC - 1 : c);
            float2 t = tab[c];
            x[i] = fmaf(t.x, x[i], t.y);
        }
    }

#pragma unroll
    for (int i = 0; i < PTS_PER_THREAD; ++i)
        out[j * n_points + base + i * BLOCK] = x[i];
}

extern "C" void kernel_launch(void* const* d_in, const int* in_sizes, int n_in,
                              void* d_out, int out_size, void* d_ws, size_t ws_size,
                              hipStream_t stream) {
    const float* points = (const float*)d_in[0];  // [NDIM=1, n_points]
    const float* theta  = (const float*)d_in[1];  // [n_theta, d]
    const float* basis  = (const float*)d_in[2];  // [2*NC, d]

    int n_points = in_sizes[0];              // NDIM == 1
    int d        = in_sizes[2] / (2 * NC);   // 30
    int n_theta  = in_sizes[1] / d;          // 8

    float2* trels = (float2*)d_ws;           // n_theta*NC float2 = 2 KB

    trels_kernel<<<1, 256, 0, stream>>>(theta, basis, trels, n_theta, d);

    int grid = n_theta * (n_points / CHUNK); // 8 * 256 = 2048 blocks
    step_kernel<<<grid, BLOCK, 0, stream>>>(points, trels, (float*)d_out, n_points);
}

// Round 2
// 74.095 us; speedup vs baseline: 1.0044x; 1.0044x over previous
//
#include <hip/hip_runtime.h>
#include <math.h>

#define NC 32
#define NSTEPS 32

constexpr int BLOCK = 256;
constexpr int PTS_PER_THREAD = 4;
constexpr int CHUNK = BLOCK * PTS_PER_THREAD; // 1024 points per block

// Single fused kernel: each block serves one theta; 32 lanes redundantly
// compute the 32 (A = e^a, B = b*phi(a)) cell coefficients for that theta
// (basis is L2-resident after the first wave of blocks), then all 256
// threads integrate 4 points each through 32 steps with the coefficient
// table in LDS (32 x float2 = 2 dword addresses per bank -> 2-way aliasing,
// which is free on gfx950 per m136).
__global__ void __launch_bounds__(BLOCK)
cpab_kernel(const float* __restrict__ points,
            const float* __restrict__ theta,
            const float* __restrict__ basis,
            float* __restrict__ out,
            int n_points, int d) {
    __shared__ float2 tab[NC];

    const int blocks_per_theta = n_points / CHUNK;
    const int j = blockIdx.x / blocks_per_theta;
    const int tid = threadIdx.x;

    if (tid < NC) {
        const int c = tid;
        const float* __restrict__ th = theta + j * d;       // wave-uniform
        const float* __restrict__ ba = basis + (2 * c) * d;
        const float* __restrict__ bb = basis + (2 * c + 1) * d;
        float a = 0.0f, b = 0.0f;
#pragma unroll 6
        for (int k = 0; k < d; ++k) {
            float t = th[k];
            a = fmaf(ba[k], t, a);
            b = fmaf(bb[k], t, b);
        }
        const float dT = 1.0f / (float)NSTEPS;
        a *= dT;
        b *= dT;
        float A = expf(a);
        // phi(a) = (e^a - 1)/a, stable small-a branch (matches reference)
        float phi = (fabsf(a) < 1e-6f) ? (1.0f + 0.5f * a) : (expm1f(a) / a);
        tab[c] = make_float2(A, b * phi);
    }
    __syncthreads();

    const int base = (blockIdx.x % blocks_per_theta) * CHUNK + tid * 4;

    float4 v = *(const float4*)(points + base); // one global_load_dwordx4
    float x[PTS_PER_THREAD] = {v.x, v.y, v.z, v.w};

#pragma unroll
    for (int s = 0; s < NSTEPS; ++s) {
#pragma unroll
        for (int i = 0; i < PTS_PER_THREAD; ++i) {
            // float-domain clamp -> v_floor + v_med3_f32 + v_cvt
            float cf = fminf(fmaxf(floorf(x[i] * (float)NC), 0.0f),
                             (float)(NC - 1));
            float2 t = tab[(int)cf];
            x[i] = fmaf(t.x, x[i], t.y); // keep arithmetic identical to R0
        }
    }

    float4 o = make_float4(x[0], x[1], x[2], x[3]);
    *(float4*)(out + j * n_points + base) = o; // one global_store_dwordx4
}

extern "C" void kernel_launch(void* const* d_in, const int* in_sizes, int n_in,
                              void* d_out, int out_size, void* d_ws, size_t ws_size,
                              hipStream_t stream) {
    const float* points = (const float*)d_in[0];  // [1, n_points]
    const float* theta  = (const float*)d_in[1];  // [n_theta, d]
    const float* basis  = (const float*)d_in[2];  // [2*NC, d]

    int n_points = in_sizes[0];
    int d        = in_sizes[2] / (2 * NC);        // 30
    int n_theta  = in_sizes[1] / d;               // 8

    int grid = n_theta * (n_points / CHUNK);      // 8 * 256 = 2048 blocks
    cpab_kernel<<<grid, BLOCK, 0, stream>>>(points, theta, basis,
                                            (float*)d_out, n_points, d);
}

// Round 3
// 71.182 us; speedup vs baseline: 1.0455x; 1.0409x over previous
//
#include <hip/hip_runtime.h>
#include <math.h>

#define NC 32
#define NSTEPS 32

constexpr int BLOCK = 256;
constexpr int PTS = 8;                 // 8 independent chains/thread for ILP
constexpr int CHUNK = BLOCK * PTS;     // 2048 points per block

// Fused kernel. State is kept pre-scaled by 32 (y = 32*x) so the per-step
// body is floor/clamp/cvt/gather/fma only (no mul). This is BIT-EXACT vs the
// reference recurrence: scaling by 2^5 commutes with fp32 rounding, so
// fmaf(A, 32x, 32B) == 32*fmaf(A, x, B) and floorf(y) == floorf(x*32).
// Table (A_c, 32*B_c) lives in LDS; gather tab[c] has <=2 unique dword
// addresses per bank (entries c and c+16 alias) -> free 2-way case.
__global__ void __launch_bounds__(BLOCK)
cpab_kernel(const float* __restrict__ points,
            const float* __restrict__ theta,
            const float* __restrict__ basis,
            float* __restrict__ out,
            int n_points, int d) {
    __shared__ float2 tab[NC];         // (A, 32*B)

    const int blocks_per_theta = n_points / CHUNK;   // 128
    const int j = blockIdx.x / blocks_per_theta;
    const int tid = threadIdx.x;

    if (tid < NC) {
        const int c = tid;
        const float* __restrict__ th = theta + j * d;
        const float* __restrict__ ba = basis + (2 * c) * d;
        const float* __restrict__ bb = basis + (2 * c + 1) * d;
        float a = 0.0f, b = 0.0f;
#pragma unroll 6
        for (int k = 0; k < d; ++k) {
            float t = th[k];
            a = fmaf(ba[k], t, a);
            b = fmaf(bb[k], t, b);
        }
        const float dT = 1.0f / (float)NSTEPS;
        a *= dT;
        b *= dT;
        float A = expf(a);
        // phi(a) = (e^a - 1)/a, stable small-a branch (matches reference)
        float phi = (fabsf(a) < 1e-6f) ? (1.0f + 0.5f * a) : (expm1f(a) / a);
        // 32*(b*phi): exact power-of-two scale of the reference's B
        tab[c] = make_float2(A, 32.0f * (b * phi));
    }
    __syncthreads();

    const int base = (blockIdx.x % blocks_per_theta) * CHUNK + tid * PTS;

    float y[PTS];
    {
        float4 v0 = *(const float4*)(points + base);
        float4 v1 = *(const float4*)(points + base + 4);
        y[0] = v0.x * 32.0f; y[1] = v0.y * 32.0f;   // exact (2^5 scale)
        y[2] = v0.z * 32.0f; y[3] = v0.w * 32.0f;
        y[4] = v1.x * 32.0f; y[5] = v1.y * 32.0f;
        y[6] = v1.z * 32.0f; y[7] = v1.w * 32.0f;
    }

    for (int s = 0; s < NSTEPS; ++s) {
#pragma unroll
        for (int i = 0; i < PTS; ++i) {
            // floor + med3 clamp in float domain; identical cell index
            float cf = fminf(fmaxf(floorf(y[i]), 0.0f), (float)(NC - 1));
            float2 t = tab[(int)cf];
            y[i] = fmaf(t.x, y[i], t.y);
        }
    }

    const float inv = 1.0f / 32.0f;                  // exact scale back
    float4 o0 = make_float4(y[0] * inv, y[1] * inv, y[2] * inv, y[3] * inv);
    float4 o1 = make_float4(y[4] * inv, y[5] * inv, y[6] * inv, y[7] * inv);
    float* op = out + j * n_points + base;
    *(float4*)op       = o0;
    *(float4*)(op + 4) = o1;
}

extern "C" void kernel_launch(void* const* d_in, const int* in_sizes, int n_in,
                              void* d_out, int out_size, void* d_ws, size_t ws_size,
                              hipStream_t stream) {
    const float* points = (const float*)d_in[0];  // [1, n_points]
    const float* theta  = (const float*)d_in[1];  // [n_theta, d]
    const float* basis  = (const float*)d_in[2];  // [2*NC, d]

    int n_points = in_sizes[0];
    int d        = in_sizes[2] / (2 * NC);        // 30
    int n_theta  = in_sizes[1] / d;               // 8

    int grid = n_theta * (n_points / CHUNK);      // 8 * 128 = 1024 blocks
    cpab_kernel<<<grid, BLOCK, 0, stream>>>(points, theta, basis,
                                            (float*)d_out, n_points, d);
}